// Round 8
// baseline (432.291 us; speedup 1.0000x reference)
//
#include <hip/hip_runtime.h>
#include <hip/hip_fp16.h>

#define IN_DIM 128
#define HID 16
#define BSHIFT 8                 // bucket = dst >> 8  (256 nodes per bucket)
#define BMASK  255
#define BCAP   9216              // bucket capacity: mean 8192 + 11 sigma
#define PCH    4096              // edges per place-block (r6 config: best)
#define PTHR   512               // place threads
#define EPT    (PCH / PTHR)      // 8 edges cached per thread

// ---------------------------------------------------------------------------
// Init: zero bucket cursors + edge-index dtype probe (int64 vs int32).
// ---------------------------------------------------------------------------
__global__ void init_kernel(const unsigned int* ei, int* flag, int* gcursor, int NB) {
    int tid = blockIdx.x * blockDim.x + threadIdx.x;
    if (tid < NB) gcursor[tid] = 0;
    if (tid == 0) {
        int zeros = 0;
        for (int j = 0; j < 8; ++j)
            if (ei[2 * j + 1] == 0u) zeros++;
        *flag = (zeros >= 7) ? 1 : 0;  // int64 little-endian => high dwords 0
    }
}

__device__ __forceinline__ int edge_at(const void* ei, long long idx, int is64) {
    if (is64) return (int)((const long long*)ei)[idx];
    return ((const int*)ei)[idx];
}

// ---------------------------------------------------------------------------
// Bin edges into fixed-capacity buckets (single pass). Packed value +
// (bucket,rank) cached in registers; one cursor atomic per (block,bucket).
// ---------------------------------------------------------------------------
__global__ __launch_bounds__(PTHR) void place_kernel(const void* ei, long long E,
        int* gcursor, unsigned int* __restrict__ binned, int NB, const int* flag) {
    __shared__ int cnt[512];
    __shared__ int wbase[512];
    int tid = threadIdx.x;
    for (int i = tid; i < NB; i += PTHR) cnt[i] = 0;
    __syncthreads();
    int is64 = *flag;
    long long e0 = (long long)blockIdx.x * PCH;

    unsigned int v[EPT];
    unsigned int br[EPT];
#pragma unroll
    for (int j = 0; j < EPT; ++j) {
        long long e = e0 + (long long)j * PTHR + tid;
        bool ok = e < E;
        int s = 0, d = 0;
        if (ok) { s = edge_at(ei, e, is64); d = edge_at(ei, E + e, is64); }
        int b = d >> BSHIFT;
        int r = ok ? atomicAdd(&cnt[b], 1) : 0;
        v[j]  = ((unsigned int)s << BSHIFT) | (unsigned int)(d & BMASK);
        br[j] = ok ? (((unsigned int)b << 16) | (unsigned int)r) : 0xFFFFFFFFu;
    }
    __syncthreads();
    for (int i = tid; i < NB; i += PTHR) {
        int c = cnt[i];
        wbase[i] = c ? atomicAdd(&gcursor[i], c) : 0;
    }
    __syncthreads();
#pragma unroll
    for (int j = 0; j < EPT; ++j) {
        if (br[j] != 0xFFFFFFFFu) {
            int b = (int)(br[j] >> 16);
            int r = (int)(br[j] & 0xFFFFu);
            int w = wbase[b] + r;
            if (w < BCAP)                          // defensive; never in practice
                binned[(size_t)b * BCAP + w] = v[j];
        }
    }
}

// ---------------------------------------------------------------------------
// Per-node degree -> dis, straight from binned (sequential 4B reads).
// ---------------------------------------------------------------------------
__global__ __launch_bounds__(256) void degdis_kernel(
        const unsigned int* __restrict__ binned, const int* __restrict__ gtotal,
        float* __restrict__ dis, int N) {
    __shared__ int cnt[256];
    int b = blockIdx.x, tid = threadIdx.x;
    cnt[tid] = 0;
    __syncthreads();
    int base = b * BCAP;
    int total = gtotal[b]; if (total > BCAP) total = BCAP;
    for (int e = tid; e < total; e += 256)
        atomicAdd(&cnt[binned[(size_t)base + e] & BMASK], 1);
    __syncthreads();
    int node = (b << BSHIFT) + tid;
    if (node < N) dis[node] = rsqrtf((float)(cnt[tid] + 1));   // +1 self loop
}

// ---------------------------------------------------------------------------
// ts = fp16( dis * (x @ W1^T) )  [N,16].  64 nodes/block, wave w owns k-slice
// [32w,32w+32): W1 wave-uniform (scalar loads), x -> registers, LDS reduce.
// ---------------------------------------------------------------------------
__global__ __launch_bounds__(256) void gemm1_kernel(
        const float* __restrict__ x, const float* __restrict__ W1,
        const float* __restrict__ dis, __half2* __restrict__ ts, int N) {
    __shared__ float red[4 * 64 * 17];
    const int tid = threadIdx.x;
    const int lane = tid & 63;
    const int wv = tid >> 6;
    const int wq = __builtin_amdgcn_readfirstlane(wv);   // wave-uniform k-quarter
    const int n = blockIdx.x * 64 + lane;

    float acc[HID];
#pragma unroll
    for (int o = 0; o < HID; ++o) acc[o] = 0.f;

    if (n < N) {
        const float* xp = &x[(size_t)n * IN_DIM + wq * 32];
        float4 xv[8];
#pragma unroll
        for (int j = 0; j < 8; ++j) xv[j] = ((const float4*)xp)[j];
        const float* wp = &W1[wq * 32];
#pragma unroll
        for (int kk = 0; kk < 32; ++kk) {
            float xs = ((const float*)xv)[kk];
#pragma unroll
            for (int o = 0; o < HID; ++o)
                acc[o] = fmaf(xs, wp[(size_t)o * IN_DIM + kk], acc[o]);
        }
    }
#pragma unroll
    for (int o = 0; o < HID; ++o)
        red[(wv * 64 + lane) * 17 + o] = acc[o];
    __syncthreads();

    const int nl = tid >> 2;
    const int og = (tid & 3) * 4;
    const int nn = blockIdx.x * 64 + nl;
    if (nn < N) {
        float s0 = 0.f, s1 = 0.f, s2 = 0.f, s3 = 0.f;
#pragma unroll
        for (int w2 = 0; w2 < 4; ++w2) {
            const float* rp = &red[(w2 * 64 + nl) * 17 + og];
            s0 += rp[0]; s1 += rp[1]; s2 += rp[2]; s3 += rp[3];
        }
        float di = dis[nn];
        __half2 p0 = __floats2half2_rn(di * s0, di * s1);
        __half2 p1 = __floats2half2_rn(di * s2, di * s3);
        float2 pk;
        pk.x = *(float*)&p0;
        pk.y = *(float*)&p1;
        ((float2*)ts)[(size_t)nn * 4 + (tid & 3)] = pk;
    }
}

// ---------------------------------------------------------------------------
// Layer-1 aggregation DIRECT from binned: LDS acc[256][17] per bucket;
// per edge gather ts[src] (32B) and ds_add 16 floats into acc[dst&255].
// Epilogue fuses self-loop + bias + ReLU + (.W2): zs = dis * z. No CSR.
// ---------------------------------------------------------------------------
__global__ __launch_bounds__(1024) void agg1_kernel(
        const unsigned int* __restrict__ binned, const int* __restrict__ gtotal,
        const __half2* __restrict__ ts, const float* __restrict__ dis,
        const float* __restrict__ b1, const float* __restrict__ W2,
        float* __restrict__ zs, int N) {
    __shared__ float acc[256 * 17];
    int b = blockIdx.x, tid = threadIdx.x;
    for (int i = tid; i < 256 * 17; i += 1024) acc[i] = 0.f;
    __syncthreads();
    int base = b * BCAP;
    int total = gtotal[b]; if (total > BCAP) total = BCAP;
    for (int e = tid; e < total; e += 1024) {
        unsigned int v = binned[(size_t)base + e];
        int src = (int)(v >> BSHIFT);
        float* ap = &acc[(v & BMASK) * 17];
        const float4* p = (const float4*)(ts + (size_t)src * 8);
        float4 A = p[0], Bv = p[1];
        const __half2* ha = (const __half2*)&A;
        const __half2* hb = (const __half2*)&Bv;
#pragma unroll
        for (int j = 0; j < 4; ++j) {
            float2 fa = __half22float2(ha[j]);
            atomicAdd(&ap[2 * j], fa.x);
            atomicAdd(&ap[2 * j + 1], fa.y);
        }
#pragma unroll
        for (int j = 0; j < 4; ++j) {
            float2 fb = __half22float2(hb[j]);
            atomicAdd(&ap[8 + 2 * j], fb.x);
            atomicAdd(&ap[8 + 2 * j + 1], fb.y);
        }
    }
    __syncthreads();
    if (tid < 256) {
        int node = (b << BSHIFT) + tid;
        if (node < N) {
            float di = dis[node];
            const float4* p = (const float4*)(ts + (size_t)node * 8);
            float4 A = p[0], Bv = p[1];
            const __half2* ha = (const __half2*)&A;
            const __half2* hb = (const __half2*)&Bv;
            const float* ac = &acc[tid * 17];
            float z = 0.f;
#pragma unroll
            for (int j = 0; j < 4; ++j) {
                float2 fa = __half22float2(ha[j]);
                float h0 = fmaxf(fmaf(di, ac[2 * j] + fa.x, b1[2 * j]), 0.f);
                float h1 = fmaxf(fmaf(di, ac[2 * j + 1] + fa.y, b1[2 * j + 1]), 0.f);
                z = fmaf(h0, W2[2 * j], z);
                z = fmaf(h1, W2[2 * j + 1], z);
            }
#pragma unroll
            for (int j = 0; j < 4; ++j) {
                float2 fb = __half22float2(hb[j]);
                float h0 = fmaxf(fmaf(di, ac[8 + 2 * j] + fb.x, b1[8 + 2 * j]), 0.f);
                float h1 = fmaxf(fmaf(di, ac[8 + 2 * j + 1] + fb.y, b1[8 + 2 * j + 1]), 0.f);
                z = fmaf(h0, W2[8 + 2 * j], z);
                z = fmaf(h1, W2[8 + 2 * j + 1], z);
            }
            zs[node] = di * z;
        }
    }
}

// ---------------------------------------------------------------------------
// Layer-2 aggregation direct from binned: scalar LDS acc2 + fused epilogue.
// ---------------------------------------------------------------------------
__global__ __launch_bounds__(1024) void agg2_kernel(
        const unsigned int* __restrict__ binned, const int* __restrict__ gtotal,
        const float* __restrict__ zs, const float* __restrict__ dis,
        const float* __restrict__ b2, float* __restrict__ out, int N) {
    __shared__ float acc2[256];
    int b = blockIdx.x, tid = threadIdx.x;
    if (tid < 256) acc2[tid] = 0.f;
    __syncthreads();
    int base = b * BCAP;
    int total = gtotal[b]; if (total > BCAP) total = BCAP;
    for (int e = tid; e < total; e += 1024) {
        unsigned int v = binned[(size_t)base + e];
        atomicAdd(&acc2[v & BMASK], zs[v >> BSHIFT]);
    }
    __syncthreads();
    if (tid < 256) {
        int node = (b << BSHIFT) + tid;
        if (node < N)
            out[node] = fmaf(dis[node], acc2[tid] + zs[node], b2[0]);
    }
}

// ---------------------------------------------------------------------------
extern "C" void kernel_launch(void* const* d_in, const int* in_sizes, int n_in,
                              void* d_out, int out_size, void* d_ws, size_t ws_size,
                              hipStream_t stream) {
    const float* x  = (const float*)d_in[0];
    const void*  ei = d_in[1];
    const float* W1 = (const float*)d_in[2];
    const float* b1 = (const float*)d_in[3];
    const float* W2 = (const float*)d_in[4];
    const float* b2 = (const float*)d_in[5];
    float* out = (float*)d_out;

    const int N = in_sizes[0] / IN_DIM;
    const long long E = in_sizes[1] / 2;
    const int NB = (N + BMASK) >> BSHIFT;      // buckets of 256 nodes (<=512)

    char* w = (char*)d_ws;
    // binned stays live through agg2 now -> ts gets its own slice.
    unsigned int* binned = (unsigned int*)w;  w += (size_t)NB * BCAP * sizeof(unsigned int);
    __half2* ts   = (__half2*)w;  w += (size_t)N * HID * sizeof(__half);
    float* zs     = (float*)w;    w += (size_t)N * sizeof(float);
    float* dis    = (float*)w;    w += (size_t)N * sizeof(float);
    int*   gcursor= (int*)w;      w += 2048 * sizeof(int);
    int*   flag   = (int*)w;

    init_kernel<<<(NB + 255) / 256, 256, 0, stream>>>(
        (const unsigned int*)ei, flag, gcursor, NB);

    int pblk = (int)((E + PCH - 1) / PCH);
    place_kernel<<<pblk, PTHR, 0, stream>>>(ei, E, gcursor, binned, NB, flag);

    degdis_kernel<<<NB, 256, 0, stream>>>(binned, gcursor, dis, N);

    int gblk = (N + 63) / 64;
    gemm1_kernel<<<gblk, 256, 0, stream>>>(x, W1, dis, ts, N);

    agg1_kernel<<<NB, 1024, 0, stream>>>(binned, gcursor, ts, dis, b1, W2, zs, N);

    agg2_kernel<<<NB, 1024, 0, stream>>>(binned, gcursor, zs, dis, b2, out, N);
}

// Round 9
// 127.088 us; speedup vs baseline: 3.4015x; 3.4015x over previous
//
#include <hip/hip_runtime.h>
#include <hip/hip_fp16.h>

#define IN_DIM 128
#define HID 16
#define BSHIFT 8                 // bucket = dst >> 8  (256 nodes per bucket)
#define BMASK  255
#define BCAP   9216              // bucket capacity: mean 8192 + 11 sigma
#define PCH    4096              // edges per place-block (best: r6 config)
#define PTHR   512               // place threads
#define EPT    (PCH / PTHR)      // 8 edges cached per thread

// ---------------------------------------------------------------------------
// Init: zero bucket cursors + edge-index dtype probe (int64 vs int32).
// ---------------------------------------------------------------------------
__global__ void init_kernel(const unsigned int* ei, int* flag, int* gcursor, int NB) {
    int tid = blockIdx.x * blockDim.x + threadIdx.x;
    if (tid < NB) gcursor[tid] = 0;
    if (tid == 0) {
        int zeros = 0;
        for (int j = 0; j < 8; ++j)
            if (ei[2 * j + 1] == 0u) zeros++;
        *flag = (zeros >= 7) ? 1 : 0;  // int64 little-endian => high dwords 0
    }
}

__device__ __forceinline__ int edge_at(const void* ei, long long idx, int is64) {
    if (is64) return (int)((const long long*)ei)[idx];
    return ((const int*)ei)[idx];
}

// ---------------------------------------------------------------------------
// Bin edges into fixed-capacity buckets (single pass). Packed value +
// (bucket,rank) cached in registers; one cursor atomic per (block,bucket).
// ---------------------------------------------------------------------------
__global__ __launch_bounds__(PTHR) void place_kernel(const void* ei, long long E,
        int* gcursor, unsigned int* __restrict__ binned, int NB, const int* flag) {
    __shared__ int cnt[512];
    __shared__ int wbase[512];
    int tid = threadIdx.x;
    for (int i = tid; i < NB; i += PTHR) cnt[i] = 0;
    __syncthreads();
    int is64 = *flag;
    long long e0 = (long long)blockIdx.x * PCH;

    unsigned int v[EPT];
    unsigned int br[EPT];
#pragma unroll
    for (int j = 0; j < EPT; ++j) {
        long long e = e0 + (long long)j * PTHR + tid;
        bool ok = e < E;
        int s = 0, d = 0;
        if (ok) { s = edge_at(ei, e, is64); d = edge_at(ei, E + e, is64); }
        int b = d >> BSHIFT;
        int r = ok ? atomicAdd(&cnt[b], 1) : 0;
        v[j]  = ((unsigned int)s << BSHIFT) | (unsigned int)(d & BMASK);
        br[j] = ok ? (((unsigned int)b << 16) | (unsigned int)r) : 0xFFFFFFFFu;
    }
    __syncthreads();
    for (int i = tid; i < NB; i += PTHR) {
        int c = cnt[i];
        wbase[i] = c ? atomicAdd(&gcursor[i], c) : 0;
    }
    __syncthreads();
#pragma unroll
    for (int j = 0; j < EPT; ++j) {
        if (br[j] != 0xFFFFFFFFu) {
            int b = (int)(br[j] >> 16);
            int r = (int)(br[j] & 0xFFFFu);
            int w = wbase[b] + r;
            if (w < BCAP)                          // defensive; never in practice
                binned[(size_t)b * BCAP + w] = v[j];
        }
    }
}

// ---------------------------------------------------------------------------
// One block (1024 thr) per bucket: LDS per-node count -> rowb/rowe/dis,
// then LDS-ranked scatter of src ids into padded csr.
// ---------------------------------------------------------------------------
__global__ __launch_bounds__(1024) void build_kernel(
        const unsigned int* __restrict__ binned, const int* __restrict__ gtotal,
        int* __restrict__ csr, int* __restrict__ rowb, int* __restrict__ rowe,
        float* __restrict__ dis, int N) {
    __shared__ int cnt[256];
    __shared__ int rowloc[256];
    int b = blockIdx.x, tid = threadIdx.x;
    int base = b * BCAP;
    int total = gtotal[b]; if (total > BCAP) total = BCAP;
    if (tid < 256) cnt[tid] = 0;
    __syncthreads();
    for (int e = tid; e < total; e += 1024)
        atomicAdd(&cnt[binned[(size_t)base + e] & BMASK], 1);
    __syncthreads();
    int c = (tid < 256) ? cnt[tid] : 0;
    if (tid < 256) rowloc[tid] = c;
    __syncthreads();
    for (int off = 1; off < 256; off <<= 1) {          // inclusive scan
        int t_ = (tid < 256 && tid >= off) ? rowloc[tid - off] : 0;
        __syncthreads();
        if (tid < 256) rowloc[tid] += t_;
        __syncthreads();
    }
    if (tid < 256) {
        int excl = rowloc[tid] - c;
        int node = (b << BSHIFT) + tid;
        if (node < N) {
            rowb[node] = base + excl;
            rowe[node] = base + excl + c;
            dis[node] = rsqrtf((float)(c + 1));        // +1 self loop
        }
        cnt[tid] = base + excl;                        // absolute cursors
    }
    __syncthreads();
    for (int e = tid; e < total; e += 1024) {
        unsigned int vv = binned[(size_t)base + e];
        int pos = atomicAdd(&cnt[vv & BMASK], 1);
        csr[pos] = (int)(vv >> BSHIFT);
    }
}

// ---------------------------------------------------------------------------
// ts = fp16( dis * (x @ W1^T) )  [N,16].  64 nodes/block, wave w owns k-slice
// [32w,32w+32): W1 wave-uniform (scalar loads), x -> registers, LDS reduce.
// ---------------------------------------------------------------------------
__global__ __launch_bounds__(256) void gemm1_kernel(
        const float* __restrict__ x, const float* __restrict__ W1,
        const float* __restrict__ dis, __half2* __restrict__ ts, int N) {
    __shared__ float red[4 * 64 * 17];
    const int tid = threadIdx.x;
    const int lane = tid & 63;
    const int wv = tid >> 6;
    const int wq = __builtin_amdgcn_readfirstlane(wv);   // wave-uniform k-quarter
    const int n = blockIdx.x * 64 + lane;

    float acc[HID];
#pragma unroll
    for (int o = 0; o < HID; ++o) acc[o] = 0.f;

    if (n < N) {
        const float* xp = &x[(size_t)n * IN_DIM + wq * 32];
        float4 xv[8];
#pragma unroll
        for (int j = 0; j < 8; ++j) xv[j] = ((const float4*)xp)[j];
        const float* wp = &W1[wq * 32];
#pragma unroll
        for (int kk = 0; kk < 32; ++kk) {
            float xs = ((const float*)xv)[kk];
#pragma unroll
            for (int o = 0; o < HID; ++o)
                acc[o] = fmaf(xs, wp[(size_t)o * IN_DIM + kk], acc[o]);
        }
    }
#pragma unroll
    for (int o = 0; o < HID; ++o)
        red[(wv * 64 + lane) * 17 + o] = acc[o];
    __syncthreads();

    const int nl = tid >> 2;
    const int og = (tid & 3) * 4;
    const int nn = blockIdx.x * 64 + nl;
    if (nn < N) {
        float s0 = 0.f, s1 = 0.f, s2 = 0.f, s3 = 0.f;
#pragma unroll
        for (int w2 = 0; w2 < 4; ++w2) {
            const float* rp = &red[(w2 * 64 + nl) * 17 + og];
            s0 += rp[0]; s1 += rp[1]; s2 += rp[2]; s3 += rp[3];
        }
        float di = dis[nn];
        __half2 p0 = __floats2half2_rn(di * s0, di * s1);
        __half2 p1 = __floats2half2_rn(di * s2, di * s3);
        float2 pk;
        pk.x = *(float*)&p0;
        pk.y = *(float*)&p1;
        ((float2*)ts)[(size_t)nn * 4 + (tid & 3)] = pk;
    }
}

// ---------------------------------------------------------------------------
// Layer-1 gather + bias + ReLU + (.W2) fused. 8 lanes/node, __half2 per lane;
// 8-deep edge batches for memory-level parallelism.
// ---------------------------------------------------------------------------
__global__ __launch_bounds__(256) void gather1_kernel(
        const int* __restrict__ rowb, const int* __restrict__ rowe,
        const int* __restrict__ csr, const __half2* __restrict__ ts,
        const float* __restrict__ dis, const float* __restrict__ b1,
        const float* __restrict__ W2, float* __restrict__ zs, int N) {
    long long gid = (long long)blockIdx.x * blockDim.x + threadIdx.x;
    int i = (int)(gid >> 3);
    int q = (int)(gid & 7);
    if (i >= N) return;
    int beg = rowb[i], end = rowe[i];
    float2 f = __half22float2(ts[(size_t)i * 8 + q]);   // self loop
    float s0 = f.x, s1 = f.y;
    int e = beg;
    for (; e + 7 < end; e += 8) {
        int ix[8];
#pragma unroll
        for (int j = 0; j < 8; ++j) ix[j] = csr[e + j];
        float2 fv[8];
#pragma unroll
        for (int j = 0; j < 8; ++j) fv[j] = __half22float2(ts[(size_t)ix[j] * 8 + q]);
#pragma unroll
        for (int j = 0; j < 8; ++j) { s0 += fv[j].x; s1 += fv[j].y; }
    }
    for (; e < end; ++e) {
        float2 fe = __half22float2(ts[(size_t)csr[e] * 8 + q]);
        s0 += fe.x; s1 += fe.y;
    }
    float di = dis[i];
    float h0 = fmaxf(fmaf(di, s0, b1[2 * q]), 0.f);
    float h1 = fmaxf(fmaf(di, s1, b1[2 * q + 1]), 0.f);
    float part = h0 * W2[2 * q] + h1 * W2[2 * q + 1];
    part += __shfl_xor(part, 1);
    part += __shfl_xor(part, 2);
    part += __shfl_xor(part, 4);
    if (q == 0) zs[i] = di * part;
}

// ---------------------------------------------------------------------------
// Layer-2 gather fused with epilogue: out[i] = dis[i]*(sum zs[src] + zs[i]) + b2
// ---------------------------------------------------------------------------
__global__ __launch_bounds__(256) void gather2_kernel(
        const int* __restrict__ rowb, const int* __restrict__ rowe,
        const int* __restrict__ csr, const float* __restrict__ zs,
        const float* __restrict__ dis, const float* __restrict__ b2,
        float* __restrict__ out, int N) {
    long long gid = (long long)blockIdx.x * blockDim.x + threadIdx.x;
    int i = (int)(gid >> 2);
    int q = (int)(gid & 3);
    if (i >= N) return;
    int beg = rowb[i], end = rowe[i];
    float s = 0.f;
    for (int e = beg + q; e < end; e += 4) s += zs[csr[e]];
    s += __shfl_xor(s, 1);
    s += __shfl_xor(s, 2);
    if (q == 0) out[i] = fmaf(dis[i], s + zs[i], b2[0]);
}

// ---------------------------------------------------------------------------
extern "C" void kernel_launch(void* const* d_in, const int* in_sizes, int n_in,
                              void* d_out, int out_size, void* d_ws, size_t ws_size,
                              hipStream_t stream) {
    const float* x  = (const float*)d_in[0];
    const void*  ei = d_in[1];
    const float* W1 = (const float*)d_in[2];
    const float* b1 = (const float*)d_in[3];
    const float* W2 = (const float*)d_in[4];
    const float* b2 = (const float*)d_in[5];
    float* out = (float*)d_out;

    const int N = in_sizes[0] / IN_DIM;
    const long long E = in_sizes[1] / 2;
    const int NB = (N + BMASK) >> BSHIFT;      // buckets of 256 nodes (<=512)

    char* w = (char*)d_ws;
    // binned (NB*BCAP u32) is dead before gemm1 writes ts (N*16 f16): alias.
    size_t binBytes = (size_t)NB * BCAP * sizeof(unsigned int);
    size_t tsBytes  = (size_t)N * HID * sizeof(__half);
    size_t sharedA  = binBytes > tsBytes ? binBytes : tsBytes;
    unsigned int* binned = (unsigned int*)w;
    __half2*      ts     = (__half2*)w;        w += sharedA;
    int*   csr    = (int*)w;    w += (size_t)NB * BCAP * sizeof(int);
    float* zs     = (float*)w;  w += (size_t)N * sizeof(float);
    float* dis    = (float*)w;  w += (size_t)N * sizeof(float);
    int*   rowb   = (int*)w;    w += (size_t)N * sizeof(int);
    int*   rowe   = (int*)w;    w += (size_t)N * sizeof(int);
    int*   gcursor= (int*)w;    w += 2048 * sizeof(int);
    int*   flag   = (int*)w;

    init_kernel<<<(NB + 255) / 256, 256, 0, stream>>>(
        (const unsigned int*)ei, flag, gcursor, NB);

    int pblk = (int)((E + PCH - 1) / PCH);
    place_kernel<<<pblk, PTHR, 0, stream>>>(ei, E, gcursor, binned, NB, flag);

    build_kernel<<<NB, 1024, 0, stream>>>(binned, gcursor, csr, rowb, rowe, dis, N);

    int gblk = (N + 63) / 64;
    gemm1_kernel<<<gblk, 256, 0, stream>>>(x, W1, dis, ts, N);

    long long g1 = (long long)N * 8;
    gather1_kernel<<<(int)((g1 + 255) / 256), 256, 0, stream>>>(
        rowb, rowe, csr, ts, dis, b1, W2, zs, N);

    long long g2 = (long long)N * 4;
    gather2_kernel<<<(int)((g2 + 255) / 256), 256, 0, stream>>>(
        rowb, rowe, csr, zs, dis, b2, out, N);
}